// Round 10
// baseline (234.426 us; speedup 1.0000x reference)
//
#include <hip/hip_runtime.h>
#include <hip/hip_bf16.h>

#define B_ 2
#define T_ 2048
#define C_ 1024
#define H_ 16
#define D_ 64

typedef unsigned short u16;
typedef __bf16 bf16x8 __attribute__((ext_vector_type(8)));
typedef float floatx4 __attribute__((ext_vector_type(4)));

__device__ __forceinline__ float bf2f(u16 u) {
  union { unsigned int i; float f; } x; x.i = ((unsigned int)u) << 16; return x.f;
}
__device__ __forceinline__ u16 f2bf(float f) {  // RNE
  union { float f; unsigned int i; } x; x.f = f;
  unsigned int r = x.i + 0x7fffu + ((x.i >> 16) & 1u);
  return (u16)(r >> 16);
}

// async 16B global -> LDS (wave-uniform base + lane*16)
__device__ __forceinline__ void gld16(void* lds, const void* g) {
  __builtin_amdgcn_global_load_lds(
      (const __attribute__((address_space(1))) unsigned int*)g,
      (__attribute__((address_space(3))) unsigned int*)lds, 16, 0, 0);
}

// ---------------------------------------------------------------------------
// Fused fp32 -> bf16 convert for x + 4 weights (one dispatch).
// ---------------------------------------------------------------------------
#define NXF4 1048576   // (B*T*C)/4
#define NWF4 262144    // (C*C)/4

__global__ __launch_bounds__(256) void cvt_all(
    const float* __restrict__ x,  const float* __restrict__ Wq,
    const float* __restrict__ Wk, const float* __restrict__ Wv,
    const float* __restrict__ Wo, u16* __restrict__ dst_base)
{
  const int i = blockIdx.x * 256 + threadIdx.x;
  const float* src; size_t off;
  if (i < NXF4)               { src = x;  off = i; }
  else if (i < NXF4 + NWF4)   { src = Wq; off = i - NXF4; }
  else if (i < NXF4 + 2*NWF4) { src = Wk; off = i - (NXF4 + NWF4); }
  else if (i < NXF4 + 3*NWF4) { src = Wv; off = i - (NXF4 + 2*NWF4); }
  else                        { src = Wo; off = i - (NXF4 + 3*NWF4); }
  float4 f = ((const float4*)src)[off];
  ushort4 o;
  o.x = f2bf(f.x); o.y = f2bf(f.y); o.z = f2bf(f.z); o.w = f2bf(f.w);
  ((ushort4*)dst_base)[i] = o;
}

// ---------------------------------------------------------------------------
// Fused QKV GEMM (round-7 proven): 128x128 tile, BK=32, gld16 staging.
// blockIdx.z: 0=Q (scaled 0.125/ln2), 1=K, 2=V transposed via LDS epilogue.
// ---------------------------------------------------------------------------
#define QSCALE 0.1803368801111f  // 0.125 / ln(2)

__global__ __launch_bounds__(256) void gemm_qkv(
    const u16* __restrict__ X, const u16* __restrict__ Wb,
    const float* __restrict__ b0, const float* __restrict__ b1,
    const float* __restrict__ b2,
    u16* __restrict__ Yq, u16* __restrict__ Yk, u16* __restrict__ Yv)
{
  const int K = C_;
  __shared__ __align__(16) u16 As[128 * 32];  // 8 KB
  __shared__ __align__(16) u16 Bs[128 * 32];  // 8 KB
  __shared__ __align__(16) u16 Es[64 * 128];  // 16 KB (V transpose round-trip)

  const int tid  = threadIdx.x;
  const int wv   = tid >> 6;
  const int lane = tid & 63;
  const int mcol = lane & 15;
  const int quad = lane >> 4;
  const int wr = wv >> 1, wc = wv & 1;
  const int m0 = blockIdx.x * 128;
  const int n0 = blockIdx.y * 128;
  const int z  = blockIdx.z;

  const u16* W = Wb + (size_t)z * C_ * C_;

  const int srow = tid >> 2;
  const int scol = (tid & 3) * 8;
  const u16* xp0 = X + (size_t)(m0 + srow) * K + scol;
  const u16* xp1 = xp0 + (size_t)64 * K;
  const u16* wp0 = W + (size_t)(n0 + srow) * K + scol;
  const u16* wp1 = wp0 + (size_t)64 * K;

  floatx4 acc[4][4] = {};

  for (int k0 = 0; k0 < K; k0 += 32) {
    gld16(&As[tid * 8],        xp0 + k0);
    gld16(&As[2048 + tid * 8], xp1 + k0);
    gld16(&Bs[tid * 8],        wp0 + k0);
    gld16(&Bs[2048 + tid * 8], wp1 + k0);
    __syncthreads();

    bf16x8 a[4], b[4];
#pragma unroll
    for (int rf = 0; rf < 4; ++rf)
      a[rf] = *(const bf16x8*)&As[(wr * 64 + rf * 16 + mcol) * 32 + quad * 8];
#pragma unroll
    for (int cf = 0; cf < 4; ++cf)
      b[cf] = *(const bf16x8*)&Bs[(wc * 64 + cf * 16 + mcol) * 32 + quad * 8];
#pragma unroll
    for (int rf = 0; rf < 4; ++rf)
#pragma unroll
      for (int cf = 0; cf < 4; ++cf)
        acc[rf][cf] = __builtin_amdgcn_mfma_f32_16x16x32_bf16(
            a[rf], b[cf], acc[rf][cf], 0, 0, 0);
    __syncthreads();
  }

  if (z == 2) {
    // --- V: LDS-transpose epilogue -> coalesced [B,H,D,T] stores ---
#pragma unroll
    for (int p = 0; p < 2; ++p) {
      __syncthreads();
      if (wc == p) {
#pragma unroll
        for (int cf = 0; cf < 4; ++cf) {
          const int rn = cf * 16 + mcol;
          const float bv = b2[n0 + p * 64 + rn];
#pragma unroll
          for (int rf = 0; rf < 4; ++rf) {
            const int gm = wr * 8 + rf * 2 + (quad >> 1);
            const int slot = gm ^ (rn & 7);
            ushort4 pk;
            pk.x = f2bf(acc[rf][cf][0] + bv);
            pk.y = f2bf(acc[rf][cf][1] + bv);
            pk.z = f2bf(acc[rf][cf][2] + bv);
            pk.w = f2bf(acc[rf][cf][3] + bv);
            *(ushort4*)&Es[rn * 128 + slot * 8 + (quad & 1) * 4] = pk;
          }
        }
      }
      __syncthreads();
      const int c = tid & 15;
      const int bb = m0 >> 11;
      const int t0 = (m0 & (T_ - 1)) + c * 8;
#pragma unroll
      for (int i = 0; i < 4; ++i) {
        const int rn = (tid >> 4) + i * 16;
        const int slot = c ^ (rn & 7);
        const uint4 val = *(const uint4*)&Es[rn * 128 + slot * 8];
        const int n = n0 + p * 64 + rn;
        const int h = n >> 6, d = n & (D_ - 1);
        *(uint4*)&Yv[(((size_t)bb * H_ + h) * D_ + d) * T_ + t0] = val;
      }
    }
  } else {
    // --- Q/K: direct [B,H,T,D] stores ---
    const float* bias = (z == 0 ? b0 : b1);
#pragma unroll
    for (int cf = 0; cf < 4; ++cf) {
      const int n = n0 + wc * 64 + cf * 16 + mcol;
      const float bv = bias[n];
      const int h = n >> 6, d = n & (D_ - 1);
#pragma unroll
      for (int rf = 0; rf < 4; ++rf) {
#pragma unroll
        for (int r = 0; r < 4; ++r) {
          const int m = m0 + wr * 64 + rf * 16 + quad * 4 + r;
          const int bb = m >> 11, t = m & (T_ - 1);
          const float v = acc[rf][cf][r] + bv;
          const size_t idx = (((size_t)bb * H_ + h) * T_ + t) * D_ + d;
          if (z == 0) Yq[idx] = f2bf(v * QSCALE);
          else        Yk[idx] = f2bf(v);
        }
      }
    }
  }
}

// ---------------------------------------------------------------------------
// Output projection GEMM (round-7 proven): 128x64 tile, BK=32, 512 blocks.
// ---------------------------------------------------------------------------
__global__ __launch_bounds__(256) void gemm_out(
    const u16* __restrict__ X, const u16* __restrict__ W,
    const float* __restrict__ bias, float* __restrict__ Yf)
{
  const int K = C_, N = C_;
  __shared__ __align__(16) u16 As[128 * 32];  // 8 KB
  __shared__ __align__(16) u16 Bs[64 * 32];   // 4 KB

  const int tid  = threadIdx.x;
  const int wv   = tid >> 6;
  const int lane = tid & 63;
  const int mcol = lane & 15;
  const int quad = lane >> 4;
  const int wr = wv >> 1, wc = wv & 1;
  const int m0 = blockIdx.x * 128;
  const int n0 = blockIdx.y * 64;

  const int srow = tid >> 2;
  const int scol = (tid & 3) * 8;
  const u16* xp0 = X + (size_t)(m0 + srow) * K + scol;
  const u16* xp1 = xp0 + (size_t)64 * K;
  const u16* wp  = W + (size_t)(n0 + srow) * K + scol;

  floatx4 acc[4][2] = {};

  for (int k0 = 0; k0 < K; k0 += 32) {
    gld16(&As[tid * 8],        xp0 + k0);
    gld16(&As[2048 + tid * 8], xp1 + k0);
    gld16(&Bs[tid * 8],        wp + k0);
    __syncthreads();

    bf16x8 a[4], b[2];
#pragma unroll
    for (int rf = 0; rf < 4; ++rf)
      a[rf] = *(const bf16x8*)&As[(wr * 64 + rf * 16 + mcol) * 32 + quad * 8];
#pragma unroll
    for (int cf = 0; cf < 2; ++cf)
      b[cf] = *(const bf16x8*)&Bs[(wc * 32 + cf * 16 + mcol) * 32 + quad * 8];
#pragma unroll
    for (int rf = 0; rf < 4; ++rf)
#pragma unroll
      for (int cf = 0; cf < 2; ++cf)
        acc[rf][cf] = __builtin_amdgcn_mfma_f32_16x16x32_bf16(
            a[rf], b[cf], acc[rf][cf], 0, 0, 0);
    __syncthreads();
  }

#pragma unroll
  for (int cf = 0; cf < 2; ++cf) {
    const int n = n0 + wc * 32 + cf * 16 + mcol;
    const float bv = bias[n];
#pragma unroll
    for (int rf = 0; rf < 4; ++rf) {
#pragma unroll
      for (int r = 0; r < 4; ++r) {
        const int m = m0 + wr * 64 + rf * 16 + quad * 4 + r;
        Yf[(size_t)m * N + n] = acc[rf][cf][r] + bv;
      }
    }
  }
}

// ---------------------------------------------------------------------------
// MFMA flash attention, causal, fixed-base softmax (log2 domain), l via
// ones-row MFMA, K/V double-buffered (round-9 proven).
// Grid 1024, ONE Q-tile per block, HEAD-MAJOR + big-tiles-first:
//   bh = bx>>5 (consecutive blocks share a head -> co-resident blocks hit
//   the same 512 KB K/V slice in L2; round-8's scatter mapping is what blew
//   FETCH_SIZE up, not the unpairing itself),
//   iq = 31-(bx&31) (descending: big tiles dispatch first, in-order backfill
//   leaves only 1-2-iter tiles in the tail).
// LDS 45 KB -> 3 blocks/CU (was grid-limited to 2 at 512 blocks).
// ---------------------------------------------------------------------------
#define KSB 4096   // u16 elems per Ks buffer (64*64)
#define VTB 5120   // u16 elems per Vt buffer (80*64; rows 64..79 = ones/zeros)

__global__ __launch_bounds__(256) void attn_flash(
    const u16* __restrict__ Q, const u16* __restrict__ K,
    const u16* __restrict__ Vg, u16* __restrict__ O)
{
  __shared__ __align__(16) u16 Ks[2 * KSB];     // 16 KB
  __shared__ __align__(16) u16 Vt[2 * VTB];     // 20 KB
  __shared__ __align__(16) u16 Ps[4][16 * 72];  // 9 KB

  const int tid  = threadIdx.x;
  const int wv   = tid >> 6;
  const int lane = tid & 63;
  const int mcol = lane & 15;
  const int quad = lane >> 4;

  const int bx = blockIdx.x;
  const int bh = bx >> 5;             // head-major
  const int iq = 31 - (bx & 31);      // big tiles first
  const size_t base  = (size_t)bh * T_ * D_;
  const size_t vbase = (size_t)bh * D_ * T_;
  const int b = bh >> 4, h = bh & (H_ - 1);

  // ones rows in BOTH Vt buffers (row 64 all-ones is swizzle-invariant)
  for (int idx = tid; idx < 16 * 64; idx += 256) {
    const u16 val = (idx < 64) ? (u16)0x3F80 : (u16)0;
    Vt[64 * 64 + idx]       = val;
    Vt[VTB + 64 * 64 + idx] = val;
  }

  const int srow = lane >> 3;
  const int sg   = (lane & 7) ^ srow;
  const int c0 = wv * 2, c1 = wv * 2 + 1;
  const int sl0 = (quad ^ (mcol & 7)) * 8;

  const int h3 = mcol >> 3, lo = mcol & 7;
  u16* psw = &Ps[wv][0];
  int colsw[4];
#pragma unroll
  for (int nt = 0; nt < 4; ++nt)
    colsw[nt] = (((nt * 2 + h3) ^ quad) * 8) + lo;
  const int g0 = quad ^ (mcol >> 2);

  const size_t koff0 = base + (size_t)(c0 * 8 + srow) * D_ + sg * 8;
  const size_t koff1 = base + (size_t)(c1 * 8 + srow) * D_ + sg * 8;
  const size_t voff0 = vbase + (size_t)(c0 * 8 + srow) * T_ + sg * 8;
  const size_t voff1 = vbase + (size_t)(c1 * 8 + srow) * T_ + sg * 8;

  const u16* qg = Q + base + (size_t)(iq * 64 + wv * 16 + mcol) * D_ + quad * 8;
  const bf16x8 qf0 = *(const bf16x8*)qg;
  const bf16x8 qf1 = *(const bf16x8*)(qg + 32);

  floatx4 oacc[5] = {};   // [0..3] D-cols; [4] rowsum via ones-row

  // ones-row init visible to all waves, then stage j=0 into buffer 0
  __syncthreads();
  gld16(&Ks[c0 * 512 + lane * 8], K  + koff0);
  gld16(&Ks[c1 * 512 + lane * 8], K  + koff1);
  gld16(&Vt[c0 * 512 + lane * 8], Vg + voff0);
  gld16(&Vt[c1 * 512 + lane * 8], Vg + voff1);

  for (int j = 0; j <= iq; ++j) {
    const int cur = j & 1;
    __syncthreads();   // drains vmcnt(0): buffer `cur` ready

    if (j < iq) {      // prefetch j+1 into the other buffer
      const int nb = cur ^ 1;
      const size_t kj = (size_t)(j + 1) * 64 * D_;
      const int    vj = (j + 1) * 64;
      gld16(&Ks[nb * KSB + c0 * 512 + lane * 8], K  + koff0 + kj);
      gld16(&Ks[nb * KSB + c1 * 512 + lane * 8], K  + koff1 + kj);
      gld16(&Vt[nb * VTB + c0 * 512 + lane * 8], Vg + voff0 + vj);
      gld16(&Vt[nb * VTB + c1 * 512 + lane * 8], Vg + voff1 + vj);
    }

    const u16* ksb = &Ks[cur * KSB];
    const u16* vtb = &Vt[cur * VTB];

    floatx4 sacc[4] = {};
#pragma unroll
    for (int nt = 0; nt < 4; ++nt) {
      const u16* kr = &ksb[(nt * 16 + mcol) * 64];
      bf16x8 kb0 = *(const bf16x8*)&kr[sl0];
      bf16x8 kb1 = *(const bf16x8*)&kr[sl0 ^ 32];
      sacc[nt] = __builtin_amdgcn_mfma_f32_16x16x32_bf16(qf0, kb0, sacc[nt], 0, 0, 0);
      sacc[nt] = __builtin_amdgcn_mfma_f32_16x16x32_bf16(qf1, kb1, sacc[nt], 0, 0, 0);
    }

    if (j == iq) {
#pragma unroll
      for (int nt = 0; nt < 4; ++nt) {
        const int col = nt * 16 + mcol;
#pragma unroll
        for (int r = 0; r < 4; ++r)
          if (col > wv * 16 + quad * 4 + r) sacc[nt][r] = -1e30f;
      }
    }

#pragma unroll
    for (int nt = 0; nt < 4; ++nt)
#pragma unroll
      for (int r = 0; r < 4; ++r) {
        const float p = exp2f(sacc[nt][r]);
        psw[(quad * 4 + r) * 72 + colsw[nt]] =
            (u16)((__float_as_uint(p) + 0x8000u) >> 16);
      }

    __builtin_amdgcn_wave_barrier();  // order Ps writes before reads

    bf16x8 pa0 = *(const bf16x8*)&psw[mcol * 72 + g0 * 8];
    bf16x8 pa1 = *(const bf16x8*)&psw[mcol * 72 + g0 * 8 + 32];
#pragma unroll
    for (int dt = 0; dt < 5; ++dt) {
      const u16* vr = &vtb[(dt * 16 + mcol) * 64];
      bf16x8 vb0 = *(const bf16x8*)&vr[sl0];
      bf16x8 vb1 = *(const bf16x8*)&vr[sl0 ^ 32];
      oacc[dt] = __builtin_amdgcn_mfma_f32_16x16x32_bf16(pa0, vb0, oacc[dt], 0, 0, 0);
      oacc[dt] = __builtin_amdgcn_mfma_f32_16x16x32_bf16(pa1, vb1, oacc[dt], 0, 0, 0);
    }
  }

  float invl[4];
#pragma unroll
  for (int r = 0; r < 4; ++r)
    invl[r] = 1.f / __shfl(oacc[4][r], lane & 48);
#pragma unroll
  for (int dt = 0; dt < 4; ++dt) {
    const int c = h * D_ + dt * 16 + mcol;
#pragma unroll
    for (int r = 0; r < 4; ++r) {
      const int t = iq * 64 + wv * 16 + quad * 4 + r;
      O[((size_t)b * T_ + t) * C_ + c] = f2bf(oacc[dt][r] * invl[r]);
    }
  }
}

// ---------------------------------------------------------------------------
extern "C" void kernel_launch(void* const* d_in, const int* in_sizes, int n_in,
                              void* d_out, int out_size, void* d_ws, size_t ws_size,
                              hipStream_t stream) {
  const float* x  = (const float*)d_in[0];
  const float* Wq = (const float*)d_in[1];
  const float* bq = (const float*)d_in[2];
  const float* Wk = (const float*)d_in[3];
  const float* bk = (const float*)d_in[4];
  const float* Wv = (const float*)d_in[5];
  const float* bv = (const float*)d_in[6];
  const float* Wo = (const float*)d_in[7];
  const float* bo = (const float*)d_in[8];
  float* out = (float*)d_out;

  const size_t NX = (size_t)B_ * T_ * C_;  // 4M
  const size_t NW = (size_t)C_ * C_;       // 1M

  u16* xb  = (u16*)d_ws;
  u16* wqb = xb  + NX;        // weights contiguous (qkv GEMM indexes by z)
  u16* wkb = wqb + NW;
  u16* wvb = wkb + NW;
  u16* wob = wvb + NW;
  u16* q   = wob + NW;        // [B,H,T,D], pre-scaled log2-domain
  u16* k   = q   + NX;        // [B,H,T,D]
  u16* v   = k   + NX;        // [B,H,D,T]
  u16* ctx = v   + NX;        // [B,T,C]

  cvt_all<<<dim3((NXF4 + 4 * NWF4) / 256), 256, 0, stream>>>(x, Wq, Wk, Wv, Wo, xb);

  gemm_qkv<<<dim3(32, 8, 3), 256, 0, stream>>>(xb, wqb, bq, bk, bv, q, k, v);

  attn_flash<<<dim3(1024), 256, 0, stream>>>(q, k, v, ctx);

  gemm_out<<<dim3(32, 16), 256, 0, stream>>>(ctx, wob, bo, out);
}

// Round 11
// 197.685 us; speedup vs baseline: 1.1859x; 1.1859x over previous
//
#include <hip/hip_runtime.h>
#include <hip/hip_bf16.h>

#define B_ 2
#define T_ 2048
#define C_ 1024
#define H_ 16
#define D_ 64

typedef unsigned short u16;
typedef __bf16 bf16x8 __attribute__((ext_vector_type(8)));
typedef float floatx4 __attribute__((ext_vector_type(4)));

__device__ __forceinline__ float bf2f(u16 u) {
  union { unsigned int i; float f; } x; x.i = ((unsigned int)u) << 16; return x.f;
}
__device__ __forceinline__ u16 f2bf(float f) {  // RNE
  union { float f; unsigned int i; } x; x.f = f;
  unsigned int r = x.i + 0x7fffu + ((x.i >> 16) & 1u);
  return (u16)(r >> 16);
}

// async 16B global -> LDS (wave-uniform base + lane*16)
__device__ __forceinline__ void gld16(void* lds, const void* g) {
  __builtin_amdgcn_global_load_lds(
      (const __attribute__((address_space(1))) unsigned int*)g,
      (__attribute__((address_space(3))) unsigned int*)lds, 16, 0, 0);
}

// ---------------------------------------------------------------------------
// Fused fp32 -> bf16 convert for x + 4 weights (one dispatch).
// ---------------------------------------------------------------------------
#define NXF4 1048576   // (B*T*C)/4
#define NWF4 262144    // (C*C)/4

__global__ __launch_bounds__(256) void cvt_all(
    const float* __restrict__ x,  const float* __restrict__ Wq,
    const float* __restrict__ Wk, const float* __restrict__ Wv,
    const float* __restrict__ Wo, u16* __restrict__ dst_base)
{
  const int i = blockIdx.x * 256 + threadIdx.x;
  const float* src; size_t off;
  if (i < NXF4)               { src = x;  off = i; }
  else if (i < NXF4 + NWF4)   { src = Wq; off = i - NXF4; }
  else if (i < NXF4 + 2*NWF4) { src = Wk; off = i - (NXF4 + NWF4); }
  else if (i < NXF4 + 3*NWF4) { src = Wv; off = i - (NXF4 + 2*NWF4); }
  else                        { src = Wo; off = i - (NXF4 + 3*NWF4); }
  float4 f = ((const float4*)src)[off];
  ushort4 o;
  o.x = f2bf(f.x); o.y = f2bf(f.y); o.z = f2bf(f.z); o.w = f2bf(f.w);
  ((ushort4*)dst_base)[i] = o;
}

// ---------------------------------------------------------------------------
// Fused QKV GEMM (round-7 proven): 128x128 tile, BK=32, gld16 staging.
// blockIdx.z: 0=Q (scaled 0.125/ln2), 1=K, 2=V transposed via LDS epilogue.
// ---------------------------------------------------------------------------
#define QSCALE 0.1803368801111f  // 0.125 / ln(2)

__global__ __launch_bounds__(256) void gemm_qkv(
    const u16* __restrict__ X, const u16* __restrict__ Wb,
    const float* __restrict__ b0, const float* __restrict__ b1,
    const float* __restrict__ b2,
    u16* __restrict__ Yq, u16* __restrict__ Yk, u16* __restrict__ Yv)
{
  const int K = C_;
  __shared__ __align__(16) u16 As[128 * 32];  // 8 KB
  __shared__ __align__(16) u16 Bs[128 * 32];  // 8 KB
  __shared__ __align__(16) u16 Es[64 * 128];  // 16 KB (V transpose round-trip)

  const int tid  = threadIdx.x;
  const int wv   = tid >> 6;
  const int lane = tid & 63;
  const int mcol = lane & 15;
  const int quad = lane >> 4;
  const int wr = wv >> 1, wc = wv & 1;
  const int m0 = blockIdx.x * 128;
  const int n0 = blockIdx.y * 128;
  const int z  = blockIdx.z;

  const u16* W = Wb + (size_t)z * C_ * C_;

  const int srow = tid >> 2;
  const int scol = (tid & 3) * 8;
  const u16* xp0 = X + (size_t)(m0 + srow) * K + scol;
  const u16* xp1 = xp0 + (size_t)64 * K;
  const u16* wp0 = W + (size_t)(n0 + srow) * K + scol;
  const u16* wp1 = wp0 + (size_t)64 * K;

  floatx4 acc[4][4] = {};

  for (int k0 = 0; k0 < K; k0 += 32) {
    gld16(&As[tid * 8],        xp0 + k0);
    gld16(&As[2048 + tid * 8], xp1 + k0);
    gld16(&Bs[tid * 8],        wp0 + k0);
    gld16(&Bs[2048 + tid * 8], wp1 + k0);
    __syncthreads();

    bf16x8 a[4], b[4];
#pragma unroll
    for (int rf = 0; rf < 4; ++rf)
      a[rf] = *(const bf16x8*)&As[(wr * 64 + rf * 16 + mcol) * 32 + quad * 8];
#pragma unroll
    for (int cf = 0; cf < 4; ++cf)
      b[cf] = *(const bf16x8*)&Bs[(wc * 64 + cf * 16 + mcol) * 32 + quad * 8];
#pragma unroll
    for (int rf = 0; rf < 4; ++rf)
#pragma unroll
      for (int cf = 0; cf < 4; ++cf)
        acc[rf][cf] = __builtin_amdgcn_mfma_f32_16x16x32_bf16(
            a[rf], b[cf], acc[rf][cf], 0, 0, 0);
    __syncthreads();
  }

  if (z == 2) {
    // --- V: LDS-transpose epilogue -> coalesced [B,H,D,T] stores ---
#pragma unroll
    for (int p = 0; p < 2; ++p) {
      __syncthreads();
      if (wc == p) {
#pragma unroll
        for (int cf = 0; cf < 4; ++cf) {
          const int rn = cf * 16 + mcol;
          const float bv = b2[n0 + p * 64 + rn];
#pragma unroll
          for (int rf = 0; rf < 4; ++rf) {
            const int gm = wr * 8 + rf * 2 + (quad >> 1);
            const int slot = gm ^ (rn & 7);
            ushort4 pk;
            pk.x = f2bf(acc[rf][cf][0] + bv);
            pk.y = f2bf(acc[rf][cf][1] + bv);
            pk.z = f2bf(acc[rf][cf][2] + bv);
            pk.w = f2bf(acc[rf][cf][3] + bv);
            *(ushort4*)&Es[rn * 128 + slot * 8 + (quad & 1) * 4] = pk;
          }
        }
      }
      __syncthreads();
      const int c = tid & 15;
      const int bb = m0 >> 11;
      const int t0 = (m0 & (T_ - 1)) + c * 8;
#pragma unroll
      for (int i = 0; i < 4; ++i) {
        const int rn = (tid >> 4) + i * 16;
        const int slot = c ^ (rn & 7);
        const uint4 val = *(const uint4*)&Es[rn * 128 + slot * 8];
        const int n = n0 + p * 64 + rn;
        const int h = n >> 6, d = n & (D_ - 1);
        *(uint4*)&Yv[(((size_t)bb * H_ + h) * D_ + d) * T_ + t0] = val;
      }
    }
  } else {
    // --- Q/K: direct [B,H,T,D] stores ---
    const float* bias = (z == 0 ? b0 : b1);
#pragma unroll
    for (int cf = 0; cf < 4; ++cf) {
      const int n = n0 + wc * 64 + cf * 16 + mcol;
      const float bv = bias[n];
      const int h = n >> 6, d = n & (D_ - 1);
#pragma unroll
      for (int rf = 0; rf < 4; ++rf) {
#pragma unroll
        for (int r = 0; r < 4; ++r) {
          const int m = m0 + wr * 64 + rf * 16 + quad * 4 + r;
          const int bb = m >> 11, t = m & (T_ - 1);
          const float v = acc[rf][cf][r] + bv;
          const size_t idx = (((size_t)bb * H_ + h) * T_ + t) * D_ + d;
          if (z == 0) Yq[idx] = f2bf(v * QSCALE);
          else        Yk[idx] = f2bf(v);
        }
      }
    }
  }
}

// ---------------------------------------------------------------------------
// Output projection GEMM (round-7 proven): 128x64 tile, BK=32, 512 blocks.
// ---------------------------------------------------------------------------
__global__ __launch_bounds__(256) void gemm_out(
    const u16* __restrict__ X, const u16* __restrict__ W,
    const float* __restrict__ bias, float* __restrict__ Yf)
{
  const int K = C_, N = C_;
  __shared__ __align__(16) u16 As[128 * 32];  // 8 KB
  __shared__ __align__(16) u16 Bs[64 * 32];   // 4 KB

  const int tid  = threadIdx.x;
  const int wv   = tid >> 6;
  const int lane = tid & 63;
  const int mcol = lane & 15;
  const int quad = lane >> 4;
  const int wr = wv >> 1, wc = wv & 1;
  const int m0 = blockIdx.x * 128;
  const int n0 = blockIdx.y * 64;

  const int srow = tid >> 2;
  const int scol = (tid & 3) * 8;
  const u16* xp0 = X + (size_t)(m0 + srow) * K + scol;
  const u16* xp1 = xp0 + (size_t)64 * K;
  const u16* wp  = W + (size_t)(n0 + srow) * K + scol;

  floatx4 acc[4][2] = {};

  for (int k0 = 0; k0 < K; k0 += 32) {
    gld16(&As[tid * 8],        xp0 + k0);
    gld16(&As[2048 + tid * 8], xp1 + k0);
    gld16(&Bs[tid * 8],        wp + k0);
    __syncthreads();

    bf16x8 a[4], b[2];
#pragma unroll
    for (int rf = 0; rf < 4; ++rf)
      a[rf] = *(const bf16x8*)&As[(wr * 64 + rf * 16 + mcol) * 32 + quad * 8];
#pragma unroll
    for (int cf = 0; cf < 2; ++cf)
      b[cf] = *(const bf16x8*)&Bs[(wc * 32 + cf * 16 + mcol) * 32 + quad * 8];
#pragma unroll
    for (int rf = 0; rf < 4; ++rf)
#pragma unroll
      for (int cf = 0; cf < 2; ++cf)
        acc[rf][cf] = __builtin_amdgcn_mfma_f32_16x16x32_bf16(
            a[rf], b[cf], acc[rf][cf], 0, 0, 0);
    __syncthreads();
  }

#pragma unroll
  for (int cf = 0; cf < 2; ++cf) {
    const int n = n0 + wc * 32 + cf * 16 + mcol;
    const float bv = bias[n];
#pragma unroll
    for (int rf = 0; rf < 4; ++rf) {
#pragma unroll
      for (int r = 0; r < 4; ++r) {
        const int m = m0 + wr * 64 + rf * 16 + quad * 4 + r;
        Yf[(size_t)m * N + n] = acc[rf][cf][r] + bv;
      }
    }
  }
}

// ---------------------------------------------------------------------------
// MFMA flash attention, causal, fixed-base softmax (log2 domain), l via
// ones-row MFMA, K/V double-buffered.
// Grid 1024, one Q-tile per block, with the XCD-PARTITION INVARIANT:
//   bh = bx & 31  => bx ≡ bh (mod 8) => all 32 blocks of head bh land on
//   XCD bh%8 (round-robin dispatch), so each XCD serves exactly 4 heads
//   = 2 MB K/V slice, fully L2-resident. (Rounds 5/6/7/9 with this property
//   measured FETCH 12.3 MB; rounds 8/10 without it: 32-62 MB.)
//   iq = 31-(bx>>5): big tiles dispatch first; CU c's resident blocks total
//   ~66 iters near-uniform, light CUs absorb the small-tile backfill.
// LDS 45 KB -> 3 blocks/CU (grid no longer the limiter).
// ---------------------------------------------------------------------------
#define KSB 4096   // u16 elems per Ks buffer (64*64)
#define VTB 5120   // u16 elems per Vt buffer (80*64; rows 64..79 = ones/zeros)

__global__ __launch_bounds__(256) void attn_flash(
    const u16* __restrict__ Q, const u16* __restrict__ K,
    const u16* __restrict__ Vg, u16* __restrict__ O)
{
  __shared__ __align__(16) u16 Ks[2 * KSB];     // 16 KB
  __shared__ __align__(16) u16 Vt[2 * VTB];     // 20 KB
  __shared__ __align__(16) u16 Ps[4][16 * 72];  // 9 KB

  const int tid  = threadIdx.x;
  const int wv   = tid >> 6;
  const int lane = tid & 63;
  const int mcol = lane & 15;
  const int quad = lane >> 4;

  const int bx = blockIdx.x;
  const int bh = bx & 31;             // XCD-partition invariant
  const int iq = 31 - (bx >> 5);      // big tiles first
  const size_t base  = (size_t)bh * T_ * D_;
  const size_t vbase = (size_t)bh * D_ * T_;
  const int b = bh >> 4, h = bh & (H_ - 1);

  // ones rows in BOTH Vt buffers (row 64 all-ones is swizzle-invariant)
  for (int idx = tid; idx < 16 * 64; idx += 256) {
    const u16 val = (idx < 64) ? (u16)0x3F80 : (u16)0;
    Vt[64 * 64 + idx]       = val;
    Vt[VTB + 64 * 64 + idx] = val;
  }

  const int srow = lane >> 3;
  const int sg   = (lane & 7) ^ srow;
  const int c0 = wv * 2, c1 = wv * 2 + 1;
  const int sl0 = (quad ^ (mcol & 7)) * 8;

  const int h3 = mcol >> 3, lo = mcol & 7;
  u16* psw = &Ps[wv][0];
  int colsw[4];
#pragma unroll
  for (int nt = 0; nt < 4; ++nt)
    colsw[nt] = (((nt * 2 + h3) ^ quad) * 8) + lo;
  const int g0 = quad ^ (mcol >> 2);

  const size_t koff0 = base + (size_t)(c0 * 8 + srow) * D_ + sg * 8;
  const size_t koff1 = base + (size_t)(c1 * 8 + srow) * D_ + sg * 8;
  const size_t voff0 = vbase + (size_t)(c0 * 8 + srow) * T_ + sg * 8;
  const size_t voff1 = vbase + (size_t)(c1 * 8 + srow) * T_ + sg * 8;

  const u16* qg = Q + base + (size_t)(iq * 64 + wv * 16 + mcol) * D_ + quad * 8;
  const bf16x8 qf0 = *(const bf16x8*)qg;
  const bf16x8 qf1 = *(const bf16x8*)(qg + 32);

  floatx4 oacc[5] = {};   // [0..3] D-cols; [4] rowsum via ones-row

  // ones-row init visible to all waves, then stage j=0 into buffer 0
  __syncthreads();
  gld16(&Ks[c0 * 512 + lane * 8], K  + koff0);
  gld16(&Ks[c1 * 512 + lane * 8], K  + koff1);
  gld16(&Vt[c0 * 512 + lane * 8], Vg + voff0);
  gld16(&Vt[c1 * 512 + lane * 8], Vg + voff1);

  for (int j = 0; j <= iq; ++j) {
    const int cur = j & 1;
    __syncthreads();   // drains vmcnt(0): buffer `cur` ready

    if (j < iq) {      // prefetch j+1 into the other buffer
      const int nb = cur ^ 1;
      const size_t kj = (size_t)(j + 1) * 64 * D_;
      const int    vj = (j + 1) * 64;
      gld16(&Ks[nb * KSB + c0 * 512 + lane * 8], K  + koff0 + kj);
      gld16(&Ks[nb * KSB + c1 * 512 + lane * 8], K  + koff1 + kj);
      gld16(&Vt[nb * VTB + c0 * 512 + lane * 8], Vg + voff0 + vj);
      gld16(&Vt[nb * VTB + c1 * 512 + lane * 8], Vg + voff1 + vj);
    }

    const u16* ksb = &Ks[cur * KSB];
    const u16* vtb = &Vt[cur * VTB];

    floatx4 sacc[4] = {};
#pragma unroll
    for (int nt = 0; nt < 4; ++nt) {
      const u16* kr = &ksb[(nt * 16 + mcol) * 64];
      bf16x8 kb0 = *(const bf16x8*)&kr[sl0];
      bf16x8 kb1 = *(const bf16x8*)&kr[sl0 ^ 32];
      sacc[nt] = __builtin_amdgcn_mfma_f32_16x16x32_bf16(qf0, kb0, sacc[nt], 0, 0, 0);
      sacc[nt] = __builtin_amdgcn_mfma_f32_16x16x32_bf16(qf1, kb1, sacc[nt], 0, 0, 0);
    }

    if (j == iq) {
#pragma unroll
      for (int nt = 0; nt < 4; ++nt) {
        const int col = nt * 16 + mcol;
#pragma unroll
        for (int r = 0; r < 4; ++r)
          if (col > wv * 16 + quad * 4 + r) sacc[nt][r] = -1e30f;
      }
    }

#pragma unroll
    for (int nt = 0; nt < 4; ++nt)
#pragma unroll
      for (int r = 0; r < 4; ++r) {
        const float p = exp2f(sacc[nt][r]);
        psw[(quad * 4 + r) * 72 + colsw[nt]] =
            (u16)((__float_as_uint(p) + 0x8000u) >> 16);
      }

    __builtin_amdgcn_wave_barrier();  // order Ps writes before reads

    bf16x8 pa0 = *(const bf16x8*)&psw[mcol * 72 + g0 * 8];
    bf16x8 pa1 = *(const bf16x8*)&psw[mcol * 72 + g0 * 8 + 32];
#pragma unroll
    for (int dt = 0; dt < 5; ++dt) {
      const u16* vr = &vtb[(dt * 16 + mcol) * 64];
      bf16x8 vb0 = *(const bf16x8*)&vr[sl0];
      bf16x8 vb1 = *(const bf16x8*)&vr[sl0 ^ 32];
      oacc[dt] = __builtin_amdgcn_mfma_f32_16x16x32_bf16(pa0, vb0, oacc[dt], 0, 0, 0);
      oacc[dt] = __builtin_amdgcn_mfma_f32_16x16x32_bf16(pa1, vb1, oacc[dt], 0, 0, 0);
    }
  }

  float invl[4];
#pragma unroll
  for (int r = 0; r < 4; ++r)
    invl[r] = 1.f / __shfl(oacc[4][r], lane & 48);
#pragma unroll
  for (int dt = 0; dt < 4; ++dt) {
    const int c = h * D_ + dt * 16 + mcol;
#pragma unroll
    for (int r = 0; r < 4; ++r) {
      const int t = iq * 64 + wv * 16 + quad * 4 + r;
      O[((size_t)b * T_ + t) * C_ + c] = f2bf(oacc[dt][r] * invl[r]);
    }
  }
}

// ---------------------------------------------------------------------------
extern "C" void kernel_launch(void* const* d_in, const int* in_sizes, int n_in,
                              void* d_out, int out_size, void* d_ws, size_t ws_size,
                              hipStream_t stream) {
  const float* x  = (const float*)d_in[0];
  const float* Wq = (const float*)d_in[1];
  const float* bq = (const float*)d_in[2];
  const float* Wk = (const float*)d_in[3];
  const float* bk = (const float*)d_in[4];
  const float* Wv = (const float*)d_in[5];
  const float* bv = (const float*)d_in[6];
  const float* Wo = (const float*)d_in[7];
  const float* bo = (const float*)d_in[8];
  float* out = (float*)d_out;

  const size_t NX = (size_t)B_ * T_ * C_;  // 4M
  const size_t NW = (size_t)C_ * C_;       // 1M

  u16* xb  = (u16*)d_ws;
  u16* wqb = xb  + NX;        // weights contiguous (qkv GEMM indexes by z)
  u16* wkb = wqb + NW;
  u16* wvb = wkb + NW;
  u16* wob = wvb + NW;
  u16* q   = wob + NW;        // [B,H,T,D], pre-scaled log2-domain
  u16* k   = q   + NX;        // [B,H,T,D]
  u16* v   = k   + NX;        // [B,H,D,T]
  u16* ctx = v   + NX;        // [B,T,C]

  cvt_all<<<dim3((NXF4 + 4 * NWF4) / 256), 256, 0, stream>>>(x, Wq, Wk, Wv, Wo, xb);

  gemm_qkv<<<dim3(32, 8, 3), 256, 0, stream>>>(xb, wqb, bq, bk, bv, q, k, v);

  attn_flash<<<dim3(1024), 256, 0, stream>>>(q, k, v, ctx);

  gemm_out<<<dim3(32, 16), 256, 0, stream>>>(ctx, wob, bo, out);
}